// Round 17
// baseline (57.690 us; speedup 1.0000x reference)
//
#include <hip/hip_runtime.h>

// ACT-R activation recurrence — async spine + GROUP-SERIAL (G=4) chain.
// s_i = sum_{j<i} ((t_i-t_j)*H)^(-decay_j),  decay_j = w0 + w1*s_j  (s_0=0)
// (reference's max(diff*H,1) never binds: min gap 0.05 days * 2160 = 108)
// out[i-1,b] = sigmoid((ln(s_i)-TAU)/S), i=1..L-1.
//
// Identity: diff^(-decay_j) = exp2(q_ij*alpha_j), q_ij = -w1*log2(diff_ij),
// alpha = s + w0/w1 > 0; masked q = -1e30 -> term 0 (alpha always > 0).
//
// R17: across R9-R16 the chain cost ~100 cyc/row regardless of structure;
// surviving model: the per-row v_readlane of a JUST-WRITTEN VGPR (full-wave
// writeback interlock) dominates. This version does ONE such hop per 4 rows:
//  per group g: read base alpha[4g..4g+3] (1 hazard) + 6 near-diag q's from
//  never-written regs; compute the 4x4 in-group triangle in SCALAR regs
//  (6 uniform exp2, depth 3); then batch-apply the 4 cols to the vector band
//  (qT, group-masked) and the folded next-block strip (qS) with good ILP.
// Workers (6, waves 1-3/5-7; wave4 idle -> SIMD0 = chain alone): Chebyshev-8
// far tiles + build qT[c+2] (group-masked), qS[c+3], qG[c+2] (16x6 in-group).

constexpr int   L  = 1024;
constexpr int   B  = 256;
constexpr int   T  = 64;
constexpr int   NT = 512;    // 8 waves: wave0 chain, wave4 idle, 6 workers

constexpr float H_CONST = 86400.0f * 0.025f;   // 2160
constexpr float TAU_C   = -0.704205679427144f;
constexpr float S_C     = 0.254893976981164f;
constexpr float LN2     = 0.69314718055994530942f;
constexpr float LOG2E   = 1.4426950408889634074f;
constexpr float BIGNEG  = -1e30f;

// cos(k*pi/16)
constexpr float CC1 = 0.98078528040323044913f;
constexpr float CC2 = 0.92387953251128675613f;
constexpr float CC3 = 0.83146961230254523708f;
constexpr float CC4 = 0.70710678118654752440f;
constexpr float CC5 = 0.55557023301960222474f;
constexpr float CC6 = 0.38268343236508977173f;
constexpr float CC7 = 0.19509032201612826785f;

__device__ static const float UNODE[8] =
  { CC1, CC3, CC5, CC7, -CC7, -CC5, -CC3, -CC1 };

typedef float f32x4 __attribute__((ext_vector_type(4)));

__device__ __forceinline__ float flog2(float x) { return __builtin_amdgcn_logf(x); }
__device__ __forceinline__ float fexp2(float x) { return __builtin_amdgcn_exp2f(x); }
__device__ __forceinline__ float rdlane(float v, int l) {
    return __uint_as_float(__builtin_amdgcn_readlane(__float_as_uint(v), l));
}

#define LOADQ(p0, p1, p2, p3, QB, c)                                \
    p0 = *(const f32x4*)((QB) + 4 * ((4 * (c) + 0) ^ xk));          \
    p1 = *(const f32x4*)((QB) + 4 * ((4 * (c) + 1) ^ xk));          \
    p2 = *(const f32x4*)((QB) + 4 * ((4 * (c) + 2) ^ xk));          \
    p3 = *(const f32x4*)((QB) + 4 * ((4 * (c) + 3) ^ xk));

// One group step (4 rows). tq/sq = quad G of the band/strip tables.
// alpha lanes of group G hold base values (in-group cols masked out of qT).
#define GSTEP(tq, sq, G) {                                         \
    const float b0 = rdlane(alpha, 4*(G));                          \
    const float b1 = rdlane(alpha, 4*(G)+1);                        \
    const float b2 = rdlane(alpha, 4*(G)+2);                        \
    const float b3 = rdlane(alpha, 4*(G)+3);                        \
    const float qA = rdlane(g0v, G), qB = rdlane(g1v, G);           \
    const float qC = rdlane(g2v, G), qD = rdlane(g3v, G);           \
    const float qE = rdlane(g4v, G), qF = rdlane(g5v, G);           \
    const float s0_ = b0;                                           \
    const float s1_ = b1 + fexp2(qA * s0_);                         \
    const float s2_ = (b2 + fexp2(qB * s0_)) + fexp2(qC * s1_);     \
    const float s3_ = ((b3 + fexp2(qD * s0_)) + fexp2(qE * s1_))    \
                      + fexp2(qF * s2_);                            \
    const int dl = lane - 4*(G);                                    \
    sigv = (dl == 0) ? s0_ : sigv;                                  \
    sigv = (dl == 1) ? s1_ : sigv;                                  \
    sigv = (dl == 2) ? s2_ : sigv;                                  \
    sigv = (dl == 3) ? s3_ : sigv;                                  \
    alpha += fexp2(tq.x * s0_);                                     \
    alpha += fexp2(tq.y * s1_);                                     \
    alpha += fexp2(tq.z * s2_);                                     \
    alpha += fexp2(tq.w * s3_);                                     \
    beta  += fexp2(sq.x * s0_);                                     \
    beta  += fexp2(sq.y * s1_);                                     \
    beta  += fexp2(sq.z * s2_);                                     \
    beta  += fexp2(sq.w * s3_); }

__global__ __launch_bounds__(NT)
void actr_kernel(const float* __restrict__ sp, const float* __restrict__ w,
                 float* __restrict__ out)
{
    __shared__ float  tH[L];
    __shared__ float  acc[L];        // far-field partial sums
    __shared__ float2 col[L];        // finalized columns {t_j, -decay_j}
    __shared__ float  qT[2][T * T];  // band q: col-group < row-group, swizzled
    __shared__ float  qS[2][T * T];  // strip tile S_b (rows blk b, cols b-1)
    __shared__ float  qG[2][16][8];  // in-group 4x4 lower-tri q, 6 per group
    __shared__ int    COLF[16];
    __shared__ int    DONE[16];

    const int bid  = blockIdx.x;
    const int b    = (bid & 7) * 32 + (bid >> 3);   // XCD write-coalescing
    const int tid  = threadIdx.x;
    const int lane = tid & 63;
    const int wv   = tid >> 6;       // 0..7
    const float w0  = w[0];
    const float w1  = w[1];
    const float CSH = w0 / w1;

    for (int i = tid; i < L; i += NT) {
        tH[i]  = sp[i * B + b] * H_CONST;
        acc[i] = 0.0f;
    }
    if (tid < 16) { COLF[tid] = 0; DONE[tid] = 0; }
    __syncthreads();

    // prologue (all 8 waves): qT blocks 0,1 (group-masked); qS blocks 1,2;
    // qG blocks 0,1.
    for (int blk = 0; blk < 2; ++blk) {
        const int base = blk * 64;
        for (int f = tid; f < T * T; f += NT) {
            const int j = f & 63, l2 = f >> 6;
            const float val = -w1 * flog2(tH[base + l2] - tH[base + j]);
            qT[blk][l2 * 64 + (j ^ (4 * (l2 & 15)))] =
                ((j >> 2) < (l2 >> 2)) ? val : BIGNEG;
        }
    }
    for (int sb = 1; sb <= 2; ++sb) {
        const int br = sb * 64, bc = (sb - 1) * 64;
        for (int f = tid; f < T * T; f += NT) {
            const int j = f & 63, i2 = f >> 6;
            qS[sb & 1][i2 * 64 + (j ^ (4 * (i2 & 15)))] =
                -w1 * flog2(tH[br + i2] - tH[bc + j]);
        }
    }
    if (tid < 192) {    // 2 blocks x 16 groups x 6 entries
        const int blk = tid / 96, rem = tid % 96;
        const int g = rem / 6, a = rem % 6;
        const int rr = (a >= 3) ? 3 : ((a >= 1) ? 2 : 1);
        const int cc = (a >= 3) ? (a - 3) : ((a == 2) ? 1 : 0);
        const int base = blk * 64 + 4 * g;
        qG[blk][g][a] = -w1 * flog2(tH[base + rr] - tH[base + cc]);
    }
    __syncthreads();    // last barrier

    if (wv == 0) {
        // ================= chain wave (SIMD0, alone) =================
        volatile int* vDONE = DONE;
        const int xk = lane & 15;
        float beta = 0.0f;           // folded strip into the NEXT block
        for (int k = 0; k < 16; ++k) {
            const int I0 = k * T;
            const int target = (k <= 1) ? 0 : k + 5;   // (k-1) far + 6 build
            while (vDONE[k] < target) __builtin_amdgcn_s_sleep(2);
            asm volatile("" ::: "memory");

            const float* qbT = &qT[k & 1][lane * 64];
            const float* qbS = &qS[(k + 1) & 1][lane * 64];
            f32x4 t0, t1, t2, t3, t4, t5, t6, t7, t8, t9, tA, tB, tC, tD, tE, tF;
            f32x4 s0, s1, s2, s3, s4, s5, s6, s7, s8, s9, sA, sB, sC, sD, sE, sF;
            LOADQ(t0, t1, t2, t3, qbT, 0)
            LOADQ(s0, s1, s2, s3, qbS, 0)
            LOADQ(t4, t5, t6, t7, qbT, 1)
            LOADQ(s4, s5, s6, s7, qbS, 1)
            LOADQ(t8, t9, tA, tB, qbT, 2)
            LOADQ(s8, s9, sA, sB, qbS, 2)
            LOADQ(tC, tD, tE, tF, qbT, 3)
            LOADQ(sC, sD, sE, sF, qbS, 3)
            // in-group q's: lane g holds group g's 6 values (never rewritten)
            const f32x4 qga = *(const f32x4*)&qG[k & 1][lane & 15][0];
            const float g0v = qga.x, g1v = qga.y, g2v = qga.z, g3v = qga.w;
            const float g4v = qG[k & 1][lane & 15][4];
            const float g5v = qG[k & 1][lane & 15][5];

            float alpha = acc[I0 + lane] + beta + CSH;   // base values
            beta = 0.0f;
            float sigv = 0.0f;
            __builtin_amdgcn_s_setprio(1);
            GSTEP(t0, s0,  0) GSTEP(t1, s1,  1) GSTEP(t2, s2,  2)
            GSTEP(t3, s3,  3) GSTEP(t4, s4,  4) GSTEP(t5, s5,  5)
            GSTEP(t6, s6,  6) GSTEP(t7, s7,  7) GSTEP(t8, s8,  8)
            GSTEP(t9, s9,  9) GSTEP(tA, sA, 10) GSTEP(tB, sB, 11)
            GSTEP(tC, sC, 12) GSTEP(tD, sD, 13) GSTEP(tE, sE, 14)
            GSTEP(tF, sF, 15)
            __builtin_amdgcn_s_setprio(0);

            const int r = I0 + lane;
            col[r] = make_float2(tH[r], -w1 * sigv);
            asm volatile("" ::: "memory");
            if (lane == 0) atomicExch(&COLF[k], 1);     // release

            if (r > 0) {
                const float act = flog2(sigv - CSH) * LN2;      // ln(s_r)
                const float e   = fexp2((TAU_C - act) * (LOG2E / S_C));
                out[(r - 1) * B + b] = 1.0f / (1.0f + e);
            }
        }
    } else if (wv != 4) {
        // ================= 6 worker waves (never on SIMD0) =================
        const int p = (wv < 4) ? (wv - 1) : (wv - 2);   // 0..5
        volatile int* vCOLF = COLF;
        for (int c = 0; c < 14; ++c) {
            while (vCOLF[c] == 0) __builtin_amdgcn_s_sleep(2);
            asm volatile("" ::: "memory");

            // --- far tiles (r, c) via Chebyshev-8: r = c+2+p+6m ---
            #pragma unroll
            for (int t2 = 0; t2 < 3; ++t2) {
                const int r = c + 2 + p + 6 * t2;
                if (r <= 15) {
                    const int m  = lane >> 3;
                    const int g  = lane & 7;
                    const float At  = tH[r * 64];
                    const float Bt  = tH[r * 64 + 63];
                    const float mid = 0.5f * (At + Bt);
                    const float hf  = 0.5f * (Bt - At);
                    const float xm  = fmaf(hf, UNODE[m], mid);
                    const float2* cb = &col[c * 64 + g * 8];
                    float gm = 0.0f;
                    #pragma unroll
                    for (int jj = 0; jj < 8; ++jj) {
                        const float2 cj = cb[jj];
                        gm += fexp2(cj.y * flog2(xm - cj.x));
                    }
                    gm += __shfl_xor(gm, 1);
                    gm += __shfl_xor(gm, 2);
                    gm += __shfl_xor(gm, 4);
                    const float g0 = rdlane(gm,  0), g1 = rdlane(gm,  8);
                    const float g2 = rdlane(gm, 16), g3 = rdlane(gm, 24);
                    const float g4 = rdlane(gm, 32), g5 = rdlane(gm, 40);
                    const float g6 = rdlane(gm, 48), g7 = rdlane(gm, 56);
                    const float u0 = g0 + g7, u1 = g1 + g6;
                    const float u2s = g2 + g5, u3 = g3 + g4;
                    const float d0 = g0 - g7, d1 = g1 - g6;
                    const float d2 = g2 - g5, d3 = g3 - g4;
                    const float a0 = 0.125f * (u0 + u1 + u2s + u3);
                    const float a2 = 0.25f * (CC2 * (u0 - u3) + CC6 * (u1 - u2s));
                    const float a4 = 0.25f * CC4 * (u0 - u1 - u2s + u3);
                    const float a6 = 0.25f * (CC6 * (u0 - u3) - CC2 * (u1 - u2s));
                    const float a1 = 0.25f * (CC1*d0 + CC3*d1 + CC5*d2 + CC7*d3);
                    const float a3 = 0.25f * (CC3*d0 - CC7*d1 - CC1*d2 - CC5*d3);
                    const float a5 = 0.25f * (CC5*d0 - CC1*d1 + CC7*d2 + CC3*d3);
                    const float a7 = 0.25f * (CC7*d0 - CC5*d1 + CC3*d2 - CC1*d3);
                    const int   i  = r * 64 + lane;
                    const float u  = (tH[i] - mid) * __builtin_amdgcn_rcpf(hf);
                    const float uu = u + u;
                    float bk1 = a7;
                    float bk  = fmaf(uu, a7, a6);
                    float t3v;
                    t3v = fmaf(uu, bk, a5) - bk1; bk1 = bk; bk = t3v;
                    t3v = fmaf(uu, bk, a4) - bk1; bk1 = bk; bk = t3v;
                    t3v = fmaf(uu, bk, a3) - bk1; bk1 = bk; bk = t3v;
                    t3v = fmaf(uu, bk, a2) - bk1; bk1 = bk; bk = t3v;
                    t3v = fmaf(uu, bk, a1) - bk1; bk1 = bk; bk = t3v;
                    atomicAdd(&acc[i], fmaf(u, bk, a0) - bk1);
                    asm volatile("" ::: "memory");
                    if (lane == 0) atomicAdd(&DONE[r], 1);
                }
            }

            // --- build qT[c+2] (group-masked), qS[c+3], qG[c+2] ---
            {
                const int blk  = c + 2;
                const float vtB = tH[blk * 64 + lane];          // block c+2
                float* qnT = &qT[blk & 1][0];
                #pragma unroll
                for (int m2 = 0; m2 < 11; ++m2) {
                    const int l2 = p + 6 * m2;
                    if (l2 < 64) {
                        const float tl2 = rdlane(vtB, l2);
                        const float val = -w1 * flog2(tl2 - vtB);
                        qnT[l2 * 64 + (lane ^ (4 * (l2 & 15)))] =
                            ((lane >> 2) < (l2 >> 2)) ? val : BIGNEG;
                    }
                }
                if (c <= 12) {      // S_{c+3}: rows block c+3, cols block c+2
                    const float vtC = tH[(c + 3) * 64 + lane];
                    float* qnS = &qS[(c + 3) & 1][0];
                    #pragma unroll
                    for (int m2 = 0; m2 < 11; ++m2) {
                        const int i2 = p + 6 * m2;
                        if (i2 < 64) {
                            const float tri = rdlane(vtC, i2);
                            qnS[i2 * 64 + (lane ^ (4 * (i2 & 15)))] =
                                -w1 * flog2(tri - vtB);
                        }
                    }
                }
                // qG for block c+2: groups g = p + 6m, lanes 0..5 = entries
                #pragma unroll
                for (int m3 = 0; m3 < 3; ++m3) {
                    const int g = p + 6 * m3;
                    if (g < 16 && lane < 6) {
                        const int rr = (lane >= 3) ? 3 : ((lane >= 1) ? 2 : 1);
                        const int cc = (lane >= 3) ? (lane - 3)
                                                   : ((lane == 2) ? 1 : 0);
                        const int base = blk * 64 + 4 * g;
                        qG[blk & 1][g][lane] =
                            -w1 * flog2(tH[base + rr] - tH[base + cc]);
                    }
                }
                asm volatile("" ::: "memory");
                if (lane == 0) atomicAdd(&DONE[blk], 1);
            }
        }
    }
    // wave 4: idle — SIMD0 belongs to the chain
}

extern "C" void kernel_launch(void* const* d_in, const int* in_sizes, int n_in,
                              void* d_out, int out_size, void* d_ws, size_t ws_size,
                              hipStream_t stream) {
    const float* sp = (const float*)d_in[0];
    const float* w  = (const float*)d_in[1];
    float* out      = (float*)d_out;
    actr_kernel<<<dim3(B), dim3(NT), 0, stream>>>(sp, w, out);
}